// Round 1
// baseline (458.928 us; speedup 1.0000x reference)
//
#include <hip/hip_runtime.h>
#include <math.h>

// GMM per-pixel sampling: out = mu[k] + exp(log_std[k]) * eps,
// k = #(cdf < u) with cdf = cumsum(softmax(pi_logits)) over K=10.
// Shapes: [B,F,T,K] = [16,256,1024,10], K innermost (rows of 40 B).
//
// Strategy: memory-bound streaming kernel. One thread handles TWO adjacent
// pixels so each per-array row-pair is 80 B = 5 aligned float4 loads
// (fully-coalesced global_load_dwordx4). All K values live in registers;
// the selected component is extracted with a cndmask chain (no gather —
// a 4 B gather would fetch nearly the same HBM lines anyway).
//
// Numerics deliberately mirror the JAX reference op-for-op:
//   e_j = expf(l_j - max); S = sum(e); cdf += e_j / S (IEEE divide per
//   element, NOT a hoisted reciprocal); strict cdf < u; clip k to K-1.

#define KMIX 10

__global__ __launch_bounds__(256) void gmm_sample_kernel(
    const float* __restrict__ mu,
    const float* __restrict__ log_std,
    const float* __restrict__ pi_logits,
    const float* __restrict__ u_cat,
    const float* __restrict__ eps,
    float* __restrict__ out,
    int npairs)
{
    int p = blockIdx.x * blockDim.x + threadIdx.x;
    if (p >= npairs) return;

    size_t base = (size_t)p * (2 * KMIX);   // element offset; byte offset 80p -> 16B aligned

    const float4* pl4 = reinterpret_cast<const float4*>(pi_logits + base);
    const float4* mu4 = reinterpret_cast<const float4*>(mu + base);
    const float4* ls4 = reinterpret_cast<const float4*>(log_std + base);

    // Issue all global loads up front for maximum MLP.
    float l[2 * KMIX], mrow[2 * KMIX], srow[2 * KMIX];
    #pragma unroll
    for (int j = 0; j < 5; ++j) {
        float4 a = pl4[j];
        float4 b = mu4[j];
        float4 c = ls4[j];
        l[4 * j + 0] = a.x; l[4 * j + 1] = a.y; l[4 * j + 2] = a.z; l[4 * j + 3] = a.w;
        mrow[4 * j + 0] = b.x; mrow[4 * j + 1] = b.y; mrow[4 * j + 2] = b.z; mrow[4 * j + 3] = b.w;
        srow[4 * j + 0] = c.x; srow[4 * j + 1] = c.y; srow[4 * j + 2] = c.z; srow[4 * j + 3] = c.w;
    }
    float2 uu = *reinterpret_cast<const float2*>(u_cat + 2 * (size_t)p);
    float2 ee = *reinterpret_cast<const float2*>(eps + 2 * (size_t)p);

    float res[2];
    #pragma unroll
    for (int t = 0; t < 2; ++t) {
        const float* lt = l + t * KMIX;

        // softmax numerator, reference order: exp(x - max)
        float m = lt[0];
        #pragma unroll
        for (int j = 1; j < KMIX; ++j) m = fmaxf(m, lt[j]);

        float e[KMIX];
        float S = 0.f;
        #pragma unroll
        for (int j = 0; j < KMIX; ++j) {
            e[j] = expf(lt[j] - m);
            S += e[j];
        }

        // cdf = cumsum(e_j / S); k = #(cdf < u), strict compare
        float uval = (t == 0) ? uu.x : uu.y;
        float cdf = 0.f;
        int k = 0;
        #pragma unroll
        for (int j = 0; j < KMIX; ++j) {
            cdf += e[j] / S;           // per-element IEEE divide, matches reference
            k += (cdf < uval) ? 1 : 0;
        }
        if (k > KMIX - 1) k = KMIX - 1;  // jnp.clip(k, 0, K-1)

        // select mu[k], log_std[k] from registers (cndmask chain)
        const float* mt = mrow + t * KMIX;
        const float* st = srow + t * KMIX;
        float mk = mt[0], sk = st[0];
        #pragma unroll
        for (int j = 1; j < KMIX; ++j) {
            bool sel = (k == j);
            mk = sel ? mt[j] : mk;
            sk = sel ? st[j] : sk;
        }

        float ev = (t == 0) ? ee.x : ee.y;
        res[t] = mk + expf(sk) * ev;
    }

    *reinterpret_cast<float2*>(out + 2 * (size_t)p) = make_float2(res[0], res[1]);
}

extern "C" void kernel_launch(void* const* d_in, const int* in_sizes, int n_in,
                              void* d_out, int out_size, void* d_ws, size_t ws_size,
                              hipStream_t stream) {
    const float* mu        = (const float*)d_in[0];
    const float* log_std   = (const float*)d_in[1];
    const float* pi_logits = (const float*)d_in[2];
    const float* u_cat     = (const float*)d_in[3];
    const float* eps       = (const float*)d_in[4];
    float* out = (float*)d_out;

    int N = in_sizes[3];          // B*F*T = 4,194,304 (even)
    int npairs = N / 2;
    int block = 256;
    int grid = (npairs + block - 1) / block;
    gmm_sample_kernel<<<grid, block, 0, stream>>>(mu, log_std, pi_logits,
                                                  u_cat, eps, out, npairs);
}

// Round 2
// 446.621 us; speedup vs baseline: 1.0276x; 1.0276x over previous
//
#include <hip/hip_runtime.h>
#include <math.h>

// GMM per-pixel sampling: out = mu[k] + exp(log_std[k]) * eps,
// k = #(cdf < u), cdf = cumsum(softmax(pi_logits)) over K=10 (innermost).
// Shapes [B,F,T,K] = [16,256,1024,10]; rows are 40 B.
//
// R2 structure: one thread = 2 adjacent pixels (row-pair = 80 B = 5 aligned
// float4 loads of pi_logits). Compute k0,k1 from registers, then GATHER
// mu[k]/log_std[k] (4 B each). Rationale: preloading mu/log_std rows (R1)
// spilled to scratch (VGPR_Count=32 < 60 live floats -> 166 us latency-bound,
// both pipes <25%). The gather hits the same 64 B HBM lines a full row read
// would (40 B rows), so traffic is identical but live state fits in ~40 VGPRs.
//
// Numerics mirror the JAX reference op-for-op: e_j = expf(l_j - max);
// S = sum(e); cdf += e_j / S (per-element IEEE divide, no hoisted
// reciprocal); strict cdf < u; clip k to K-1.

#define KMIX 10

__device__ __forceinline__ int compute_k(const float* lt, float uval) {
    float m = lt[0];
    #pragma unroll
    for (int j = 1; j < KMIX; ++j) m = fmaxf(m, lt[j]);

    float e[KMIX];
    float S = 0.f;
    #pragma unroll
    for (int j = 0; j < KMIX; ++j) {
        e[j] = expf(lt[j] - m);
        S += e[j];
    }

    float cdf = 0.f;
    int k = 0;
    #pragma unroll
    for (int j = 0; j < KMIX; ++j) {
        cdf += e[j] / S;            // per-element IEEE divide, matches reference
        k += (cdf < uval) ? 1 : 0;  // strict compare, matches reference
    }
    return (k > KMIX - 1) ? (KMIX - 1) : k;   // jnp.clip(k, 0, K-1)
}

__global__ __launch_bounds__(256) void gmm_sample_kernel(
    const float* __restrict__ mu,
    const float* __restrict__ log_std,
    const float* __restrict__ pi_logits,
    const float* __restrict__ u_cat,
    const float* __restrict__ eps,
    float* __restrict__ out,
    int npairs)
{
    int p = blockIdx.x * blockDim.x + threadIdx.x;
    if (p >= npairs) return;

    size_t base = (size_t)p * (2 * KMIX);   // byte offset 80p -> 16 B aligned

    // pi_logits row-pair: 80 B = 5 x float4, fully coalesced.
    const float4* pl4 = reinterpret_cast<const float4*>(pi_logits + base);
    float l[2 * KMIX];
    #pragma unroll
    for (int j = 0; j < 5; ++j) {
        float4 a = pl4[j];
        l[4 * j + 0] = a.x; l[4 * j + 1] = a.y;
        l[4 * j + 2] = a.z; l[4 * j + 3] = a.w;
    }
    float2 uu = *reinterpret_cast<const float2*>(u_cat + 2 * (size_t)p);
    float2 ee = *reinterpret_cast<const float2*>(eps + 2 * (size_t)p);

    // Component indices for both pixels first, so the 4 gathers below issue
    // back-to-back (one memory round trip, maximum MLP).
    int k0 = compute_k(l, uu.x);
    int k1 = compute_k(l + KMIX, uu.y);

    size_t i0 = base + (size_t)k0;
    size_t i1 = base + KMIX + (size_t)k1;
    float mk0 = mu[i0];
    float sk0 = log_std[i0];
    float mk1 = mu[i1];
    float sk1 = log_std[i1];

    float2 r;
    r.x = mk0 + expf(sk0) * ee.x;
    r.y = mk1 + expf(sk1) * ee.y;
    *reinterpret_cast<float2*>(out + 2 * (size_t)p) = r;
}

extern "C" void kernel_launch(void* const* d_in, const int* in_sizes, int n_in,
                              void* d_out, int out_size, void* d_ws, size_t ws_size,
                              hipStream_t stream) {
    const float* mu        = (const float*)d_in[0];
    const float* log_std   = (const float*)d_in[1];
    const float* pi_logits = (const float*)d_in[2];
    const float* u_cat     = (const float*)d_in[3];
    const float* eps       = (const float*)d_in[4];
    float* out = (float*)d_out;

    int N = in_sizes[3];          // B*F*T = 4,194,304 (even)
    int npairs = N / 2;
    int block = 256;
    int grid = (npairs + block - 1) / block;
    gmm_sample_kernel<<<grid, block, 0, stream>>>(mu, log_std, pi_logits,
                                                  u_cat, eps, out, npairs);
}